// Round 17
// baseline (194.555 us; speedup 1.0000x reference)
//
#include <hip/hip_runtime.h>
#include <hip/hip_bf16.h>

namespace {

constexpr int N_NODES = 100000;
constexpr int N_EDGES = 3200000;
constexpr int D = 16;
constexpr int H = 64;
constexpr int C = 10;
constexpr int BLK = 256;
constexpr int BLKS = 512;                    // sort-kernel block size
constexpr int NBN = (N_NODES + BLK - 1) / BLK;  // 391

constexpr int PA = 32;                       // k_agg partition (nodes per agg block)
constexpr int NP = (N_NODES + PA - 1) / PA;  // 3125 agg partitions

constexpr int CBN = 256;                     // nodes per coarse sort bin
constexpr int NC = (N_NODES + CBN - 1) / CBN;  // 391 coarse bins
constexpr int NPTR = NC * CBN + 1;           // node_ptr entries (100097)

constexpr int NBB = 1024;                    // binning blocks
constexpr int EC = N_EDGES / NBB;            // 3125 edges per binning block
constexpr int REC2_CAP = N_EDGES + 7 * N_NODES;  // padded records upper bound

__device__ inline unsigned short f2bf(float f) {  // fp32 -> bf16 bits, RNE
  unsigned u = __float_as_uint(f);
  return (unsigned short)((u + 0x7FFFu + ((u >> 16) & 1u)) >> 16);
}
__device__ inline float bf2f(unsigned short b) {  // bf16 bits -> fp32 (exact)
  return __uint_as_float(((unsigned)b) << 16);
}

// Per-block LDS histogram over coarse bins, written coalesced (no global atomics).
__global__ void k_bincount(const int* __restrict__ col, int* __restrict__ blk_hist) {
  __shared__ int lh[NC];
  for (int i = threadIdx.x; i < NC; i += BLKS) lh[i] = 0;
  __syncthreads();
  const int b = blockIdx.x;
  const int e0 = b * EC, e1 = e0 + EC;
  for (int e = e0 + threadIdx.x; e < e1; e += 4 * BLKS) {
    int cc[4]; bool ok[4];
#pragma unroll
    for (int j = 0; j < 4; ++j) {
      int ee = e + j * BLKS;
      ok[j] = ee < e1;
      cc[j] = ok[j] ? col[ee] : 0;
    }
#pragma unroll
    for (int j = 0; j < 4; ++j)
      if (ok[j]) atomicAdd(&lh[cc[j] >> 8], 1);
  }
  __syncthreads();
  for (int i = threadIdx.x; i < NC; i += BLKS)
    blk_hist[(size_t)b * NC + i] = lh[i];
}

// Per-bin exclusive prefix across the NBB blocks (in place) + bin totals.
__global__ void k_colscan(int* __restrict__ blk_hist, int* __restrict__ bin_cnt) {
  const int i = blockIdx.x;
  const int t = threadIdx.x;  // 0..255, thread owns 4 consecutive b's
  int v[4];
  int s = 0;
#pragma unroll
  for (int j = 0; j < 4; ++j) {
    v[j] = blk_hist[(size_t)(t * 4 + j) * NC + i];
    s += v[j];
  }
  const int lane = t & 63;
  int incl = s;
#pragma unroll
  for (int off = 1; off < 64; off <<= 1) {
    int y = __shfl_up(incl, off, 64);
    if (lane >= off) incl += y;
  }
  __shared__ int wsum[4];
  const int w = t >> 6;
  if (lane == 63) wsum[w] = incl;
  __syncthreads();
  int wbase = 0;
#pragma unroll
  for (int k = 0; k < 4; ++k) wbase += (k < w) ? wsum[k] : 0;
  int excl = wbase + incl - s;
#pragma unroll
  for (int j = 0; j < 4; ++j) {
    blk_hist[(size_t)(t * 4 + j) * NC + i] = excl;
    excl += v[j];
  }
  if (t == BLK - 1) bin_cnt[i] = excl;  // column total
}

// Exclusive scan of src[n<=2048] -> dst. Single block, 1024 thr, double-buffered.
__global__ void k_scan(const int* __restrict__ src, int* __restrict__ dst, int n,
                       int sentinel) {
  __shared__ int s0[2048], s1[2048];
  const int t = threadIdx.x;
  int v0 = (t < n) ? src[t] : 0;
  int v1 = (t + 1024 < n) ? src[t + 1024] : 0;
  s0[t] = v0; s0[t + 1024] = v1;
  __syncthreads();
  int* cur = s0; int* nxt = s1;
  for (int off = 1; off < 2048; off <<= 1) {
    nxt[t] = cur[t] + (t >= off ? cur[t - off] : 0);
    int i1 = t + 1024;
    nxt[i1] = cur[i1] + (i1 >= off ? cur[i1 - off] : 0);
    __syncthreads();
    int* tmp = cur; cur = nxt; nxt = tmp;
  }
  if (t < n) dst[t] = cur[t] - v0;
  if (t + 1024 < n) dst[t + 1024] = cur[t + 1024] - v1;
  if (t == 0 && sentinel >= 0) dst[n] = sentinel;
}

// Scatter records (row | c_local<<17, ew) into coarse-bin order using LDS
// cursors seeded from the scan. Unrolled 8x: independent atomic->store chains.
__global__ void k_binscatter(const int* __restrict__ row, const int* __restrict__ col,
                             const float* __restrict__ ew, const int* __restrict__ coarse_ptr,
                             const int* __restrict__ blk_hist, uint2* __restrict__ recs) {
  __shared__ int lcur[NC];
  const int b = blockIdx.x;
  for (int i = threadIdx.x; i < NC; i += BLKS)
    lcur[i] = coarse_ptr[i] + blk_hist[(size_t)b * NC + i];
  __syncthreads();
  const int e0 = b * EC, e1 = e0 + EC;
  for (int e = e0 + threadIdx.x; e < e1; e += 8 * BLKS) {
    int cc[8], rr[8]; float ww[8]; bool ok[8];
#pragma unroll
    for (int j = 0; j < 8; ++j) {
      int ee = e + j * BLKS;
      ok[j] = ee < e1;
      cc[j] = ok[j] ? col[ee] : 0;
      rr[j] = ok[j] ? row[ee] : 0;
      ww[j] = ok[j] ? ew[ee] : 0.f;
    }
#pragma unroll
    for (int j = 0; j < 8; ++j) {
      if (ok[j]) {
        int c = cc[j];
        int pos = atomicAdd(&lcur[c >> 8], 1);  // LDS atomic (independent chains)
        recs[pos] = make_uint2((unsigned)rr[j] | ((unsigned)(c & (CBN - 1)) << 17),
                               __float_as_uint(ww[j]));
      }
    }
  }
}

// Per-coarse-bin per-node counts (256 LDS counters); padded (roundup-8) totals.
__global__ void k_cntnode(const uint2* __restrict__ recs, const int* __restrict__ coarse_ptr,
                          int* __restrict__ cnt_g, int* __restrict__ pad_cnt) {
  __shared__ int cnt[CBN];
  __shared__ int ws[4];
  const int b = blockIdx.x;
  const int tid = threadIdx.x;
  if (tid < CBN) cnt[tid] = 0;
  __syncthreads();
  const int beg = coarse_ptr[b], end = coarse_ptr[b + 1];
  for (int p = beg + tid; p < end; p += 4 * BLKS) {
    unsigned xx[4]; bool ok[4];
#pragma unroll
    for (int j = 0; j < 4; ++j) {
      int pp = p + j * BLKS;
      ok[j] = pp < end;
      xx[j] = ok[j] ? recs[pp].x : 0u;
    }
#pragma unroll
    for (int j = 0; j < 4; ++j)
      if (ok[j]) atomicAdd(&cnt[xx[j] >> 17], 1);
  }
  __syncthreads();
  if (tid < CBN) {
    int c = cnt[tid];
    cnt_g[b * CBN + tid] = c;
    int pv = (c + 7) & ~7;
#pragma unroll
    for (int m = 1; m < 64; m <<= 1) pv += __shfl_xor(pv, m, 64);
    if ((tid & 63) == 0) ws[tid >> 6] = pv;
  }
  __syncthreads();
  if (tid == 0) pad_cnt[b] = ws[0] + ws[1] + ws[2] + ws[3];
}

// Counting-sort scatter within each coarse bin into padded node runs (pads
// (0,0)). Unrolled 4x for independent atomic->store chains.
__global__ void k_sortscatter(const uint2* __restrict__ recs, const int* __restrict__ coarse_ptr,
                              const int* __restrict__ cnt_g, const int* __restrict__ pad_ptr,
                              int* __restrict__ node_ptr, uint2* __restrict__ recs2) {
  __shared__ int cur[CBN];
  __shared__ int fin[CBN];
  __shared__ int wsum[4];
  const int b = blockIdx.x;
  const int tid = threadIdx.x;
  int pc = 0, incl = 0;
  if (tid < CBN) {
    pc = (cnt_g[b * CBN + tid] + 7) & ~7;
    incl = pc;
    const int lane = tid & 63;
#pragma unroll
    for (int off = 1; off < 64; off <<= 1) {
      int y = __shfl_up(incl, off, 64);
      if (lane >= off) incl += y;
    }
    if (lane == 63) wsum[tid >> 6] = incl;
  }
  __syncthreads();
  if (tid < CBN) {
    const int w = tid >> 6;
    int wb = 0;
#pragma unroll
    for (int k = 0; k < 4; ++k) wb += (k < w) ? wsum[k] : 0;
    int excl = wb + incl - pc + pad_ptr[b];
    cur[tid] = excl;
    fin[tid] = excl + pc;
    node_ptr[b * CBN + tid] = excl;
    if (b == NC - 1 && tid == CBN - 1) node_ptr[NC * CBN] = excl + pc;
  }
  __syncthreads();
  const int beg = coarse_ptr[b], end = coarse_ptr[b + 1];
  for (int p = beg + tid; p < end; p += 4 * BLKS) {
    uint2 r[4]; bool ok[4];
#pragma unroll
    for (int j = 0; j < 4; ++j) {
      int pp = p + j * BLKS;
      ok[j] = pp < end;
      r[j] = ok[j] ? recs[pp] : make_uint2(0u, 0u);
    }
#pragma unroll
    for (int j = 0; j < 4; ++j) {
      if (ok[j]) {
        int pos = atomicAdd(&cur[r[j].x >> 17], 1);  // LDS atomic
        recs2[pos] = make_uint2(r[j].x & 0x1FFFF, r[j].y);
      }
    }
  }
  __syncthreads();
  if (tid < CBN) {
    for (int q = cur[tid]; q < fin[tid]; ++q) recs2[q] = make_uint2(0u, 0u);
  }
}

// dinv from padded runs (pads have w=0, contribute nothing). deg starts at 1.
__global__ void k_dinv2(const int* __restrict__ node_ptr, const uint2* __restrict__ recs2,
                        float* __restrict__ dinv) {
  int v = blockIdx.x * BLK + threadIdx.x;
  if (v >= N_NODES) return;
  float s = 1.0f;
  int e = node_ptr[v + 1];
  for (int p = node_ptr[v]; p < e; ++p) s += __uint_as_float(recs2[p].y);
  dinv[v] = s > 0.f ? rsqrtf(fmaxf(s, 1e-30f)) : 0.f;
}

// outd[v,:] = bf16( dinv[v] * (h[v,:] @ W^T) )  — layer-0 table only.
__global__ void k_lin(const float* __restrict__ hin, const float* __restrict__ W,
                      const float* __restrict__ dinv, unsigned short* __restrict__ outd) {
  __shared__ float sW[D * D];
  sW[threadIdx.x] = W[threadIdx.x];
  __syncthreads();
  int v = blockIdx.x * BLK + threadIdx.x;
  if (v >= N_NODES) return;
  float hv[D];
  const float4* hp = reinterpret_cast<const float4*>(hin + (size_t)v * D);
#pragma unroll
  for (int c = 0; c < 4; ++c) {
    float4 t = hp[c];
    hv[4 * c + 0] = t.x; hv[4 * c + 1] = t.y;
    hv[4 * c + 2] = t.z; hv[4 * c + 3] = t.w;
  }
  float dv = dinv[v];
  unsigned short ob[D];
#pragma unroll
  for (int j = 0; j < D; ++j) {
    float s = 0.f;
#pragma unroll
    for (int k = 0; k < D; ++k) s += hv[k] * sW[j * D + k];
    ob[j] = f2bf(s * dv);
  }
  uint4 w0, w1;
  w0.x = (unsigned)ob[0]  | ((unsigned)ob[1]  << 16);
  w0.y = (unsigned)ob[2]  | ((unsigned)ob[3]  << 16);
  w0.z = (unsigned)ob[4]  | ((unsigned)ob[5]  << 16);
  w0.w = (unsigned)ob[6]  | ((unsigned)ob[7]  << 16);
  w1.x = (unsigned)ob[8]  | ((unsigned)ob[9]  << 16);
  w1.y = (unsigned)ob[10] | ((unsigned)ob[11] << 16);
  w1.z = (unsigned)ob[12] | ((unsigned)ob[13] << 16);
  w1.w = (unsigned)ob[14] | ((unsigned)ob[15] << 16);
  uint4* op = reinterpret_cast<uint4*>(outd + (size_t)v * D);
  op[0] = w0;
  op[1] = w1;
}

// PURE PULL aggregate + fused nodeNN/tanh/LeakyReLU/LayerNorm.
// Inner loop: 2-deep FULL pipeline — gathers for iter i+1 issued before the
// FMAs of iter i (one full iteration of slack for gather latency); rec lines
// prefetched 2 ahead. All stages in named registers (no runtime indexing).
//   MODE 0: write h as bf16; MODE 1: fused next-layer lin -> bf16 outd_next
template <int MODE>
__global__ void k_agg(const int* __restrict__ node_ptr, const uint2* __restrict__ recs2,
                      const float* __restrict__ dinv, const unsigned short* __restrict__ outd,
                      const float* __restrict__ Wn, const float* __restrict__ nb,
                      const float* __restrict__ cb, const float* __restrict__ lg,
                      const float* __restrict__ lb,
                      const float* __restrict__ Wlin_next,     // MODE 1
                      unsigned short* __restrict__ outd_next) {
  __shared__ float sacc[PA * 17];
  __shared__ float sdinv[PA];
  __shared__ float sWT[D * D];    // sWT[k*D + j] = Wn[j*D + k]
  __shared__ float snb[D], scb[D], slg[D], slb[D];
  __shared__ float sWT2[(MODE == 1) ? D * D : 1];   // next lin, transposed
  const int b = blockIdx.x;
  const int base = b * PA;
  const int tid = threadIdx.x;

  sWT[tid] = Wn[(tid & 15) * D + (tid >> 4)];
  if (tid < D) {
    snb[tid] = nb[tid]; scb[tid] = cb[tid];
    slg[tid] = lg[tid]; slb[tid] = lb[tid];
  }
  if constexpr (MODE == 1) {
    sWT2[tid] = Wlin_next[(tid & 15) * D + (tid >> 4)];
  }
  if (tid < PA) {
    int v = base + tid;
    sdinv[tid] = (v < N_NODES) ? dinv[v] : 0.f;
  }
  __syncthreads();

  const int g = tid >> 4;
  const int l = tid & 15;
#pragma unroll
  for (int i = 0; i < PA / 16; ++i) {
    const int n = g + 16 * i;
    const int v = base + n;
    float acc = (v < N_NODES) ? bf2f(outd[(size_t)v * D + l]) : 0.f;  // self-loop
    int p = node_ptr[v];
    const int e = node_ptr[v + 1];
    uint4 cA0, cA1, cA2, cA3;  // rec line (weights) for current iter
    uint4 cB0, cB1, cB2, cB3;  // rec line for next iter
    float gA0, gA1, gA2, gA3, gA4, gA5, gA6, gA7;  // gathers for current iter
    if (p < e) {
      const uint4* rp = reinterpret_cast<const uint4*>(recs2 + p);
      cA0 = rp[0]; cA1 = rp[1]; cA2 = rp[2]; cA3 = rp[3];
      gA0 = bf2f(outd[(size_t)cA0.x * D + l]);
      gA1 = bf2f(outd[(size_t)cA0.z * D + l]);
      gA2 = bf2f(outd[(size_t)cA1.x * D + l]);
      gA3 = bf2f(outd[(size_t)cA1.z * D + l]);
      gA4 = bf2f(outd[(size_t)cA2.x * D + l]);
      gA5 = bf2f(outd[(size_t)cA2.z * D + l]);
      gA6 = bf2f(outd[(size_t)cA3.x * D + l]);
      gA7 = bf2f(outd[(size_t)cA3.z * D + l]);
      const int pn = (p + 8 < e) ? p + 8 : p;
      const uint4* rpn = reinterpret_cast<const uint4*>(recs2 + pn);
      cB0 = rpn[0]; cB1 = rpn[1]; cB2 = rpn[2]; cB3 = rpn[3];
    }
    for (; p < e; p += 8) {  // runs are exact multiples of 8
      // issue gathers for NEXT iteration (from the arrived cB line)
      float gB0 = bf2f(outd[(size_t)cB0.x * D + l]);
      float gB1 = bf2f(outd[(size_t)cB0.z * D + l]);
      float gB2 = bf2f(outd[(size_t)cB1.x * D + l]);
      float gB3 = bf2f(outd[(size_t)cB1.z * D + l]);
      float gB4 = bf2f(outd[(size_t)cB2.x * D + l]);
      float gB5 = bf2f(outd[(size_t)cB2.z * D + l]);
      float gB6 = bf2f(outd[(size_t)cB3.x * D + l]);
      float gB7 = bf2f(outd[(size_t)cB3.z * D + l]);
      // rec line for p+16 (clamped, branchless-valid)
      const int pn2 = (p + 16 < e) ? p + 16 : p;
      const uint4* rp2 = reinterpret_cast<const uint4*>(recs2 + pn2);
      uint4 nC0 = rp2[0], nC1 = rp2[1], nC2 = rp2[2], nC3 = rp2[3];
      // consume CURRENT iteration (gathers issued one iteration ago)
      acc = fmaf(__uint_as_float(cA0.y), gA0, acc);
      acc = fmaf(__uint_as_float(cA0.w), gA1, acc);
      acc = fmaf(__uint_as_float(cA1.y), gA2, acc);
      acc = fmaf(__uint_as_float(cA1.w), gA3, acc);
      acc = fmaf(__uint_as_float(cA2.y), gA4, acc);
      acc = fmaf(__uint_as_float(cA2.w), gA5, acc);
      acc = fmaf(__uint_as_float(cA3.y), gA6, acc);
      acc = fmaf(__uint_as_float(cA3.w), gA7, acc);
      // rotate stages
      cA0 = cB0; cA1 = cB1; cA2 = cB2; cA3 = cB3;
      gA0 = gB0; gA1 = gB1; gA2 = gB2; gA3 = gB3;
      gA4 = gB4; gA5 = gB5; gA6 = gB6; gA7 = gB7;
      cB0 = nC0; cB1 = nC1; cB2 = nC2; cB3 = nC3;
    }
    sacc[n * 17 + l] = acc;
  }
  __syncthreads();

  // epilogue: nodeNN tanh(W·(dinv·agg) + nb) + cb, LeakyReLU, LN, then MODE
#pragma unroll
  for (int nb0 = 0; nb0 < PA / 16; ++nb0) {
    int n = nb0 * 16 + g;
    int v = base + n;
    float s = 0.f;
#pragma unroll
    for (int k = 0; k < D; ++k) s += sacc[n * 17 + k] * sWT[k * D + l];
    s = snb[l] + sdinv[n] * s;
    float u = tanhf(s) + scb[l];
    u = u > 0.f ? u : 0.2f * u;  // LeakyReLU(0.2)
    float mu = u;
#pragma unroll
    for (int m = 1; m < 16; m <<= 1) mu += __shfl_xor(mu, m, 64);
    mu *= (1.0f / D);
    float dd = u - mu;
    float var = dd * dd;
#pragma unroll
    for (int m = 1; m < 16; m <<= 1) var += __shfl_xor(var, m, 64);
    var *= (1.0f / D);
    float inv = rsqrtf(var + 1e-5f);
    float hval = dd * inv * slg[l] + slb[l];

    if constexpr (MODE == 0) {
      if (v < N_NODES) outd_next[(size_t)v * D + l] = f2bf(hval);
    } else {
      // broadcast the node's full h row into registers (16 shfl, no LDS)
      float hreg[D];
#pragma unroll
      for (int k = 0; k < D; ++k) hreg[k] = __shfl(hval, k, 16);
      float s2 = 0.f;
#pragma unroll
      for (int k = 0; k < D; ++k) s2 = fmaf(hreg[k], sWT2[k * D + l], s2);
      if (v < N_NODES) outd_next[(size_t)v * D + l] = f2bf(s2 * sdinv[n]);
    }
  }
}

// out[v,:] = relu(h @ w1^T + b1) @ w2^T + b2   (h in bf16, node per thread)
__global__ void k_cls(const unsigned short* __restrict__ h, const float* __restrict__ w1,
                      const float* __restrict__ b1, const float* __restrict__ w2,
                      const float* __restrict__ b2, float* __restrict__ out) {
  __shared__ float sw1[H * D];
  __shared__ float sb1[H];
  __shared__ float sw2[C * H];
  __shared__ float sb2[C];
  for (int i = threadIdx.x; i < H * D; i += BLK) sw1[i] = w1[i];
  for (int i = threadIdx.x; i < H; i += BLK) sb1[i] = b1[i];
  for (int i = threadIdx.x; i < C * H; i += BLK) sw2[i] = w2[i];
  for (int i = threadIdx.x; i < C; i += BLK) sb2[i] = b2[i];
  __syncthreads();
  int v = blockIdx.x * BLK + threadIdx.x;
  if (v >= N_NODES) return;
  const uint4* hp = reinterpret_cast<const uint4*>(h + (size_t)v * D);
  uint4 hb0 = hp[0], hb1 = hp[1];
  float hv[D];
  unsigned wrd[8] = {hb0.x, hb0.y, hb0.z, hb0.w, hb1.x, hb1.y, hb1.z, hb1.w};
#pragma unroll
  for (int c = 0; c < 8; ++c) {
    hv[2 * c + 0] = bf2f((unsigned short)(wrd[c] & 0xFFFFu));
    hv[2 * c + 1] = bf2f((unsigned short)(wrd[c] >> 16));
  }
  float oc[C];
#pragma unroll
  for (int c = 0; c < C; ++c) oc[c] = sb2[c];
#pragma unroll
  for (int j = 0; j < H; ++j) {
    float s = sb1[j];
#pragma unroll
    for (int k = 0; k < D; ++k) s = fmaf(hv[k], sw1[j * D + k], s);
    s = fmaxf(s, 0.f);
#pragma unroll
    for (int c = 0; c < C; ++c) oc[c] = fmaf(s, sw2[c * H + j], oc[c]);
  }
#pragma unroll
  for (int c = 0; c < C; ++c) out[(size_t)v * C + c] = oc[c];
}

inline char* align_up(char* p, size_t a) {
  return (char*)(((uintptr_t)p + a - 1) & ~(uintptr_t)(a - 1));
}

}  // namespace

extern "C" void kernel_launch(void* const* d_in, const int* in_sizes, int n_in,
                              void* d_out, int out_size, void* d_ws, size_t ws_size,
                              hipStream_t stream) {
  const float* x         = (const float*)d_in[0];
  const int*   edge_idx  = (const int*)d_in[1];   // [2, E]
  const float* edge_attr = (const float*)d_in[2];
  const float* lin_w  = (const float*)d_in[4];
  const float* conv_b = (const float*)d_in[5];
  const float* node_w = (const float*)d_in[6];
  const float* node_b = (const float*)d_in[7];
  const float* ln_g   = (const float*)d_in[8];
  const float* ln_b   = (const float*)d_in[9];
  const float* w1     = (const float*)d_in[10];
  const float* b1     = (const float*)d_in[11];
  const float* w2     = (const float*)d_in[12];
  const float* b2     = (const float*)d_in[13];
  float* out = (float*)d_out;

  const int* row = edge_idx;            // source
  const int* col = edge_idx + N_EDGES;  // target

  // workspace layout — r12 aliasing discipline (proven):
  // blk_hist (1.6 MB, dead after k_binscatter) at head of recs2 region;
  // outbA/outbB (bf16, 3.2 MB each) alias recs (dead after sort).
  // Layer-2 agg writes h (bf16) back into outbA (dead once agg1 finished).
  char* p = (char*)d_ws;
  int*   bin_cnt    = (int*)p;   p = align_up(p + sizeof(int) * NC, 256);
  int*   coarse_ptr = (int*)p;   p = align_up(p + sizeof(int) * (NC + 1), 256);
  int*   pad_cnt    = (int*)p;   p = align_up(p + sizeof(int) * NC, 256);
  int*   pad_ptr    = (int*)p;   p = align_up(p + sizeof(int) * (NC + 1), 256);
  int*   cnt_g      = (int*)p;   p = align_up(p + sizeof(int) * (size_t)(NC * CBN), 256);
  int*   node_ptr   = (int*)p;   p = align_up(p + sizeof(int) * (size_t)NPTR, 256);
  float* dinv       = (float*)p; p = align_up(p + sizeof(float) * N_NODES, 256);
  char*  recs_mem   = p;         p = align_up(p + sizeof(uint2) * (size_t)N_EDGES, 256);
  uint2* recs2      = (uint2*)p; p = align_up(p + sizeof(uint2) * (size_t)REC2_CAP, 256);

  uint2* recs = (uint2*)recs_mem;
  unsigned short* outbA = (unsigned short*)recs_mem;  // alias (recs dead after sort)
  unsigned short* outbB = (unsigned short*)align_up(
      recs_mem + sizeof(unsigned short) * (size_t)N_NODES * D, 256);
  int* blk_hist = (int*)recs2;   // alias (dead before recs2 is written)

  // ---- one-time build: coarse sort (256-node bins) -> per-node runs ----
  k_bincount<<<NBB, BLKS, 0, stream>>>(col, blk_hist);
  k_colscan<<<NC, BLK, 0, stream>>>(blk_hist, bin_cnt);
  k_scan<<<1, 1024, 0, stream>>>(bin_cnt, coarse_ptr, NC, N_EDGES);
  k_binscatter<<<NBB, BLKS, 0, stream>>>(row, col, edge_attr, coarse_ptr, blk_hist, recs);
  k_cntnode<<<NC, BLKS, 0, stream>>>(recs, coarse_ptr, cnt_g, pad_cnt);
  k_scan<<<1, 1024, 0, stream>>>(pad_cnt, pad_ptr, NC, -1);
  k_sortscatter<<<NC, BLKS, 0, stream>>>(recs, coarse_ptr, cnt_g, pad_ptr, node_ptr, recs2);
  k_dinv2<<<NBN, BLK, 0, stream>>>(node_ptr, recs2, dinv);

  // ---- layers: lin #2 fused into agg #1; classifier separate (MODE 0) ----
  k_lin<<<NBN, BLK, 0, stream>>>(x, lin_w, dinv, outbA);
  k_agg<1><<<NP, BLK, 0, stream>>>(node_ptr, recs2, dinv, outbA,
                                   node_w, node_b, conv_b, ln_g, ln_b,
                                   lin_w + D * D, outbB);
  k_agg<0><<<NP, BLK, 0, stream>>>(node_ptr, recs2, dinv, outbB,
                                   node_w + D * D, node_b + D, conv_b + D,
                                   ln_g + D, ln_b + D,
                                   nullptr, outbA);
  k_cls<<<NBN, BLK, 0, stream>>>(outbA, w1, b1, w2, b2, out);
}

// Round 18
// 188.642 us; speedup vs baseline: 1.0313x; 1.0313x over previous
//
#include <hip/hip_runtime.h>
#include <hip/hip_bf16.h>

namespace {

constexpr int N_NODES = 100000;
constexpr int N_EDGES = 3200000;
constexpr int D = 16;
constexpr int H = 64;
constexpr int C = 10;
constexpr int BLK = 256;
constexpr int BLKS = 512;                    // sort-kernel block size
constexpr int NBN = (N_NODES + BLK - 1) / BLK;  // 391

constexpr int PA = 32;                       // k_agg partition (nodes per agg block)
constexpr int NP = (N_NODES + PA - 1) / PA;  // 3125 agg partitions

constexpr int CBN = 256;                     // nodes per coarse sort bin
constexpr int NC = (N_NODES + CBN - 1) / CBN;  // 391 coarse bins
constexpr int NPTR = NC * CBN + 1;           // node_ptr entries (100097)

constexpr int NBB = 1024;                    // binning blocks
constexpr int EC = N_EDGES / NBB;            // 3125 edges per binning block
constexpr int REC2_CAP = N_EDGES + 7 * N_NODES;  // padded records upper bound

__device__ inline unsigned short f2bf(float f) {  // fp32 -> bf16 bits, RNE
  unsigned u = __float_as_uint(f);
  return (unsigned short)((u + 0x7FFFu + ((u >> 16) & 1u)) >> 16);
}
__device__ inline float bf2f(unsigned short b) {  // bf16 bits -> fp32 (exact)
  return __uint_as_float(((unsigned)b) << 16);
}

// Per-block LDS histogram over coarse bins, written coalesced (no global atomics).
__global__ void k_bincount(const int* __restrict__ col, int* __restrict__ blk_hist) {
  __shared__ int lh[NC];
  for (int i = threadIdx.x; i < NC; i += BLKS) lh[i] = 0;
  __syncthreads();
  const int b = blockIdx.x;
  const int e0 = b * EC, e1 = e0 + EC;
  for (int e = e0 + threadIdx.x; e < e1; e += 4 * BLKS) {
    int cc[4]; bool ok[4];
#pragma unroll
    for (int j = 0; j < 4; ++j) {
      int ee = e + j * BLKS;
      ok[j] = ee < e1;
      cc[j] = ok[j] ? col[ee] : 0;
    }
#pragma unroll
    for (int j = 0; j < 4; ++j)
      if (ok[j]) atomicAdd(&lh[cc[j] >> 8], 1);
  }
  __syncthreads();
  for (int i = threadIdx.x; i < NC; i += BLKS)
    blk_hist[(size_t)b * NC + i] = lh[i];
}

// Per-bin exclusive prefix across the NBB blocks (in place) + bin totals.
__global__ void k_colscan(int* __restrict__ blk_hist, int* __restrict__ bin_cnt) {
  const int i = blockIdx.x;
  const int t = threadIdx.x;  // 0..255, thread owns 4 consecutive b's
  int v[4];
  int s = 0;
#pragma unroll
  for (int j = 0; j < 4; ++j) {
    v[j] = blk_hist[(size_t)(t * 4 + j) * NC + i];
    s += v[j];
  }
  const int lane = t & 63;
  int incl = s;
#pragma unroll
  for (int off = 1; off < 64; off <<= 1) {
    int y = __shfl_up(incl, off, 64);
    if (lane >= off) incl += y;
  }
  __shared__ int wsum[4];
  const int w = t >> 6;
  if (lane == 63) wsum[w] = incl;
  __syncthreads();
  int wbase = 0;
#pragma unroll
  for (int k = 0; k < 4; ++k) wbase += (k < w) ? wsum[k] : 0;
  int excl = wbase + incl - s;
#pragma unroll
  for (int j = 0; j < 4; ++j) {
    blk_hist[(size_t)(t * 4 + j) * NC + i] = excl;
    excl += v[j];
  }
  if (t == BLK - 1) bin_cnt[i] = excl;  // column total
}

// Exclusive scan of src[n<=2048] -> dst. Single block, 1024 thr, double-buffered.
__global__ void k_scan(const int* __restrict__ src, int* __restrict__ dst, int n,
                       int sentinel) {
  __shared__ int s0[2048], s1[2048];
  const int t = threadIdx.x;
  int v0 = (t < n) ? src[t] : 0;
  int v1 = (t + 1024 < n) ? src[t + 1024] : 0;
  s0[t] = v0; s0[t + 1024] = v1;
  __syncthreads();
  int* cur = s0; int* nxt = s1;
  for (int off = 1; off < 2048; off <<= 1) {
    nxt[t] = cur[t] + (t >= off ? cur[t - off] : 0);
    int i1 = t + 1024;
    nxt[i1] = cur[i1] + (i1 >= off ? cur[i1 - off] : 0);
    __syncthreads();
    int* tmp = cur; cur = nxt; nxt = tmp;
  }
  if (t < n) dst[t] = cur[t] - v0;
  if (t + 1024 < n) dst[t + 1024] = cur[t + 1024] - v1;
  if (t == 0 && sentinel >= 0) dst[n] = sentinel;
}

// Scatter records (row | c_local<<17, ew) into coarse-bin order using LDS
// cursors seeded from the scan. Unrolled 8x: independent atomic->store chains.
__global__ void k_binscatter(const int* __restrict__ row, const int* __restrict__ col,
                             const float* __restrict__ ew, const int* __restrict__ coarse_ptr,
                             const int* __restrict__ blk_hist, uint2* __restrict__ recs) {
  __shared__ int lcur[NC];
  const int b = blockIdx.x;
  for (int i = threadIdx.x; i < NC; i += BLKS)
    lcur[i] = coarse_ptr[i] + blk_hist[(size_t)b * NC + i];
  __syncthreads();
  const int e0 = b * EC, e1 = e0 + EC;
  for (int e = e0 + threadIdx.x; e < e1; e += 8 * BLKS) {
    int cc[8], rr[8]; float ww[8]; bool ok[8];
#pragma unroll
    for (int j = 0; j < 8; ++j) {
      int ee = e + j * BLKS;
      ok[j] = ee < e1;
      cc[j] = ok[j] ? col[ee] : 0;
      rr[j] = ok[j] ? row[ee] : 0;
      ww[j] = ok[j] ? ew[ee] : 0.f;
    }
#pragma unroll
    for (int j = 0; j < 8; ++j) {
      if (ok[j]) {
        int c = cc[j];
        int pos = atomicAdd(&lcur[c >> 8], 1);  // LDS atomic (independent chains)
        recs[pos] = make_uint2((unsigned)rr[j] | ((unsigned)(c & (CBN - 1)) << 17),
                               __float_as_uint(ww[j]));
      }
    }
  }
}

// Per-coarse-bin per-node counts (256 LDS counters); padded (roundup-8) totals.
__global__ void k_cntnode(const uint2* __restrict__ recs, const int* __restrict__ coarse_ptr,
                          int* __restrict__ cnt_g, int* __restrict__ pad_cnt) {
  __shared__ int cnt[CBN];
  __shared__ int ws[4];
  const int b = blockIdx.x;
  const int tid = threadIdx.x;
  if (tid < CBN) cnt[tid] = 0;
  __syncthreads();
  const int beg = coarse_ptr[b], end = coarse_ptr[b + 1];
  for (int p = beg + tid; p < end; p += 4 * BLKS) {
    unsigned xx[4]; bool ok[4];
#pragma unroll
    for (int j = 0; j < 4; ++j) {
      int pp = p + j * BLKS;
      ok[j] = pp < end;
      xx[j] = ok[j] ? recs[pp].x : 0u;
    }
#pragma unroll
    for (int j = 0; j < 4; ++j)
      if (ok[j]) atomicAdd(&cnt[xx[j] >> 17], 1);
  }
  __syncthreads();
  if (tid < CBN) {
    int c = cnt[tid];
    cnt_g[b * CBN + tid] = c;
    int pv = (c + 7) & ~7;
#pragma unroll
    for (int m = 1; m < 64; m <<= 1) pv += __shfl_xor(pv, m, 64);
    if ((tid & 63) == 0) ws[tid >> 6] = pv;
  }
  __syncthreads();
  if (tid == 0) pad_cnt[b] = ws[0] + ws[1] + ws[2] + ws[3];
}

// Counting-sort scatter within each coarse bin into padded node runs (pads
// (0,0)). Unrolled 4x for independent atomic->store chains.
__global__ void k_sortscatter(const uint2* __restrict__ recs, const int* __restrict__ coarse_ptr,
                              const int* __restrict__ cnt_g, const int* __restrict__ pad_ptr,
                              int* __restrict__ node_ptr, uint2* __restrict__ recs2) {
  __shared__ int cur[CBN];
  __shared__ int fin[CBN];
  __shared__ int wsum[4];
  const int b = blockIdx.x;
  const int tid = threadIdx.x;
  int pc = 0, incl = 0;
  if (tid < CBN) {
    pc = (cnt_g[b * CBN + tid] + 7) & ~7;
    incl = pc;
    const int lane = tid & 63;
#pragma unroll
    for (int off = 1; off < 64; off <<= 1) {
      int y = __shfl_up(incl, off, 64);
      if (lane >= off) incl += y;
    }
    if (lane == 63) wsum[tid >> 6] = incl;
  }
  __syncthreads();
  if (tid < CBN) {
    const int w = tid >> 6;
    int wb = 0;
#pragma unroll
    for (int k = 0; k < 4; ++k) wb += (k < w) ? wsum[k] : 0;
    int excl = wb + incl - pc + pad_ptr[b];
    cur[tid] = excl;
    fin[tid] = excl + pc;
    node_ptr[b * CBN + tid] = excl;
    if (b == NC - 1 && tid == CBN - 1) node_ptr[NC * CBN] = excl + pc;
  }
  __syncthreads();
  const int beg = coarse_ptr[b], end = coarse_ptr[b + 1];
  for (int p = beg + tid; p < end; p += 4 * BLKS) {
    uint2 r[4]; bool ok[4];
#pragma unroll
    for (int j = 0; j < 4; ++j) {
      int pp = p + j * BLKS;
      ok[j] = pp < end;
      r[j] = ok[j] ? recs[pp] : make_uint2(0u, 0u);
    }
#pragma unroll
    for (int j = 0; j < 4; ++j) {
      if (ok[j]) {
        int pos = atomicAdd(&cur[r[j].x >> 17], 1);  // LDS atomic
        recs2[pos] = make_uint2(r[j].x & 0x1FFFF, r[j].y);
      }
    }
  }
  __syncthreads();
  if (tid < CBN) {
    for (int q = cur[tid]; q < fin[tid]; ++q) recs2[q] = make_uint2(0u, 0u);
  }
}

// dinv from padded runs (pads have w=0, contribute nothing). deg starts at 1.
__global__ void k_dinv2(const int* __restrict__ node_ptr, const uint2* __restrict__ recs2,
                        float* __restrict__ dinv) {
  int v = blockIdx.x * BLK + threadIdx.x;
  if (v >= N_NODES) return;
  float s = 1.0f;
  int e = node_ptr[v + 1];
  for (int p = node_ptr[v]; p < e; ++p) s += __uint_as_float(recs2[p].y);
  dinv[v] = s > 0.f ? rsqrtf(fmaxf(s, 1e-30f)) : 0.f;
}

// outd[v,:] = bf16( dinv[v] * (h[v,:] @ W^T) )  — layer-0 table only.
__global__ void k_lin(const float* __restrict__ hin, const float* __restrict__ W,
                      const float* __restrict__ dinv, unsigned short* __restrict__ outd) {
  __shared__ float sW[D * D];
  sW[threadIdx.x] = W[threadIdx.x];
  __syncthreads();
  int v = blockIdx.x * BLK + threadIdx.x;
  if (v >= N_NODES) return;
  float hv[D];
  const float4* hp = reinterpret_cast<const float4*>(hin + (size_t)v * D);
#pragma unroll
  for (int c = 0; c < 4; ++c) {
    float4 t = hp[c];
    hv[4 * c + 0] = t.x; hv[4 * c + 1] = t.y;
    hv[4 * c + 2] = t.z; hv[4 * c + 3] = t.w;
  }
  float dv = dinv[v];
  unsigned short ob[D];
#pragma unroll
  for (int j = 0; j < D; ++j) {
    float s = 0.f;
#pragma unroll
    for (int k = 0; k < D; ++k) s += hv[k] * sW[j * D + k];
    ob[j] = f2bf(s * dv);
  }
  uint4 w0, w1;
  w0.x = (unsigned)ob[0]  | ((unsigned)ob[1]  << 16);
  w0.y = (unsigned)ob[2]  | ((unsigned)ob[3]  << 16);
  w0.z = (unsigned)ob[4]  | ((unsigned)ob[5]  << 16);
  w0.w = (unsigned)ob[6]  | ((unsigned)ob[7]  << 16);
  w1.x = (unsigned)ob[8]  | ((unsigned)ob[9]  << 16);
  w1.y = (unsigned)ob[10] | ((unsigned)ob[11] << 16);
  w1.z = (unsigned)ob[12] | ((unsigned)ob[13] << 16);
  w1.w = (unsigned)ob[14] | ((unsigned)ob[15] << 16);
  uint4* op = reinterpret_cast<uint4*>(outd + (size_t)v * D);
  op[0] = w0;
  op[1] = w1;
}

// PURE PULL aggregate + fused nodeNN/tanh/LeakyReLU/LayerNorm, then:
//   MODE 0: write h as bf16 (classifier runs as separate node-per-thread kernel)
//   MODE 1: fused next-layer lin -> bf16 outd_next
// (r16 configuration — measured best; r17's deeper pipeline regressed.)
template <int MODE>
__global__ void k_agg(const int* __restrict__ node_ptr, const uint2* __restrict__ recs2,
                      const float* __restrict__ dinv, const unsigned short* __restrict__ outd,
                      const float* __restrict__ Wn, const float* __restrict__ nb,
                      const float* __restrict__ cb, const float* __restrict__ lg,
                      const float* __restrict__ lb,
                      const float* __restrict__ Wlin_next,     // MODE 1
                      unsigned short* __restrict__ outd_next) {
  __shared__ float sacc[PA * 17];
  __shared__ float sdinv[PA];
  __shared__ float sWT[D * D];    // sWT[k*D + j] = Wn[j*D + k]
  __shared__ float snb[D], scb[D], slg[D], slb[D];
  __shared__ float sWT2[(MODE == 1) ? D * D : 1];   // next lin, transposed
  const int b = blockIdx.x;
  const int base = b * PA;
  const int tid = threadIdx.x;

  sWT[tid] = Wn[(tid & 15) * D + (tid >> 4)];
  if (tid < D) {
    snb[tid] = nb[tid]; scb[tid] = cb[tid];
    slg[tid] = lg[tid]; slb[tid] = lb[tid];
  }
  if constexpr (MODE == 1) {
    sWT2[tid] = Wlin_next[(tid & 15) * D + (tid >> 4)];
  }
  if (tid < PA) {
    int v = base + tid;
    sdinv[tid] = (v < N_NODES) ? dinv[v] : 0.f;
  }
  __syncthreads();

  const int g = tid >> 4;
  const int l = tid & 15;
#pragma unroll
  for (int i = 0; i < PA / 16; ++i) {
    const int n = g + 16 * i;
    const int v = base + n;
    float acc = (v < N_NODES) ? bf2f(outd[(size_t)v * D + l]) : 0.f;  // self-loop
    int p = node_ptr[v];
    const int e = node_ptr[v + 1];
    uint4 a0, a1, a2, a3;
    if (p < e) {
      const uint4* rp = reinterpret_cast<const uint4*>(recs2 + p);
      a0 = rp[0]; a1 = rp[1]; a2 = rp[2]; a3 = rp[3];
    }
    for (; p < e; p += 8) {  // runs are exact multiples of 8
      const int pn = (p + 8 < e) ? p + 8 : p;
      const uint4* rpn = reinterpret_cast<const uint4*>(recs2 + pn);
      uint4 b0 = rpn[0], b1_ = rpn[1], b2_ = rpn[2], b3 = rpn[3];
      float g0 = bf2f(outd[(size_t)a0.x * D + l]);
      float g1 = bf2f(outd[(size_t)a0.z * D + l]);
      float g2 = bf2f(outd[(size_t)a1.x * D + l]);
      float g3 = bf2f(outd[(size_t)a1.z * D + l]);
      float g4 = bf2f(outd[(size_t)a2.x * D + l]);
      float g5 = bf2f(outd[(size_t)a2.z * D + l]);
      float g6 = bf2f(outd[(size_t)a3.x * D + l]);
      float g7 = bf2f(outd[(size_t)a3.z * D + l]);
      acc = fmaf(__uint_as_float(a0.y), g0, acc);
      acc = fmaf(__uint_as_float(a0.w), g1, acc);
      acc = fmaf(__uint_as_float(a1.y), g2, acc);
      acc = fmaf(__uint_as_float(a1.w), g3, acc);
      acc = fmaf(__uint_as_float(a2.y), g4, acc);
      acc = fmaf(__uint_as_float(a2.w), g5, acc);
      acc = fmaf(__uint_as_float(a3.y), g6, acc);
      acc = fmaf(__uint_as_float(a3.w), g7, acc);
      a0 = b0; a1 = b1_; a2 = b2_; a3 = b3;
    }
    sacc[n * 17 + l] = acc;
  }
  __syncthreads();

  // epilogue: nodeNN tanh(W·(dinv·agg) + nb) + cb, LeakyReLU, LN, then MODE
#pragma unroll
  for (int nb0 = 0; nb0 < PA / 16; ++nb0) {
    int n = nb0 * 16 + g;
    int v = base + n;
    float s = 0.f;
#pragma unroll
    for (int k = 0; k < D; ++k) s += sacc[n * 17 + k] * sWT[k * D + l];
    s = snb[l] + sdinv[n] * s;
    float u = tanhf(s) + scb[l];
    u = u > 0.f ? u : 0.2f * u;  // LeakyReLU(0.2)
    float mu = u;
#pragma unroll
    for (int m = 1; m < 16; m <<= 1) mu += __shfl_xor(mu, m, 64);
    mu *= (1.0f / D);
    float dd = u - mu;
    float var = dd * dd;
#pragma unroll
    for (int m = 1; m < 16; m <<= 1) var += __shfl_xor(var, m, 64);
    var *= (1.0f / D);
    float inv = rsqrtf(var + 1e-5f);
    float hval = dd * inv * slg[l] + slb[l];

    if constexpr (MODE == 0) {
      if (v < N_NODES) outd_next[(size_t)v * D + l] = f2bf(hval);
    } else {
      // broadcast the node's full h row into registers (16 shfl, no LDS)
      float hreg[D];
#pragma unroll
      for (int k = 0; k < D; ++k) hreg[k] = __shfl(hval, k, 16);
      float s2 = 0.f;
#pragma unroll
      for (int k = 0; k < D; ++k) s2 = fmaf(hreg[k], sWT2[k * D + l], s2);
      if (v < N_NODES) outd_next[(size_t)v * D + l] = f2bf(s2 * sdinv[n]);
    }
  }
}

// out[v,:] = relu(h @ w1^T + b1) @ w2^T + b2   (h in bf16, node per thread)
__global__ void k_cls(const unsigned short* __restrict__ h, const float* __restrict__ w1,
                      const float* __restrict__ b1, const float* __restrict__ w2,
                      const float* __restrict__ b2, float* __restrict__ out) {
  __shared__ float sw1[H * D];
  __shared__ float sb1[H];
  __shared__ float sw2[C * H];
  __shared__ float sb2[C];
  for (int i = threadIdx.x; i < H * D; i += BLK) sw1[i] = w1[i];
  for (int i = threadIdx.x; i < H; i += BLK) sb1[i] = b1[i];
  for (int i = threadIdx.x; i < C * H; i += BLK) sw2[i] = w2[i];
  for (int i = threadIdx.x; i < C; i += BLK) sb2[i] = b2[i];
  __syncthreads();
  int v = blockIdx.x * BLK + threadIdx.x;
  if (v >= N_NODES) return;
  const uint4* hp = reinterpret_cast<const uint4*>(h + (size_t)v * D);
  uint4 hb0 = hp[0], hb1 = hp[1];
  float hv[D];
  unsigned wrd[8] = {hb0.x, hb0.y, hb0.z, hb0.w, hb1.x, hb1.y, hb1.z, hb1.w};
#pragma unroll
  for (int c = 0; c < 8; ++c) {
    hv[2 * c + 0] = bf2f((unsigned short)(wrd[c] & 0xFFFFu));
    hv[2 * c + 1] = bf2f((unsigned short)(wrd[c] >> 16));
  }
  float oc[C];
#pragma unroll
  for (int c = 0; c < C; ++c) oc[c] = sb2[c];
#pragma unroll
  for (int j = 0; j < H; ++j) {
    float s = sb1[j];
#pragma unroll
    for (int k = 0; k < D; ++k) s = fmaf(hv[k], sw1[j * D + k], s);
    s = fmaxf(s, 0.f);
#pragma unroll
    for (int c = 0; c < C; ++c) oc[c] = fmaf(s, sw2[c * H + j], oc[c]);
  }
#pragma unroll
  for (int c = 0; c < C; ++c) out[(size_t)v * C + c] = oc[c];
}

inline char* align_up(char* p, size_t a) {
  return (char*)(((uintptr_t)p + a - 1) & ~(uintptr_t)(a - 1));
}

}  // namespace

extern "C" void kernel_launch(void* const* d_in, const int* in_sizes, int n_in,
                              void* d_out, int out_size, void* d_ws, size_t ws_size,
                              hipStream_t stream) {
  const float* x         = (const float*)d_in[0];
  const int*   edge_idx  = (const int*)d_in[1];   // [2, E]
  const float* edge_attr = (const float*)d_in[2];
  const float* lin_w  = (const float*)d_in[4];
  const float* conv_b = (const float*)d_in[5];
  const float* node_w = (const float*)d_in[6];
  const float* node_b = (const float*)d_in[7];
  const float* ln_g   = (const float*)d_in[8];
  const float* ln_b   = (const float*)d_in[9];
  const float* w1     = (const float*)d_in[10];
  const float* b1     = (const float*)d_in[11];
  const float* w2     = (const float*)d_in[12];
  const float* b2     = (const float*)d_in[13];
  float* out = (float*)d_out;

  const int* row = edge_idx;            // source
  const int* col = edge_idx + N_EDGES;  // target

  // workspace layout — r12 aliasing discipline (proven):
  // blk_hist (1.6 MB, dead after k_binscatter) at head of recs2 region;
  // outbA/outbB (bf16, 3.2 MB each) alias recs (dead after sort).
  // Layer-2 agg writes h (bf16) back into outbA (dead once agg1 finished).
  char* p = (char*)d_ws;
  int*   bin_cnt    = (int*)p;   p = align_up(p + sizeof(int) * NC, 256);
  int*   coarse_ptr = (int*)p;   p = align_up(p + sizeof(int) * (NC + 1), 256);
  int*   pad_cnt    = (int*)p;   p = align_up(p + sizeof(int) * NC, 256);
  int*   pad_ptr    = (int*)p;   p = align_up(p + sizeof(int) * (NC + 1), 256);
  int*   cnt_g      = (int*)p;   p = align_up(p + sizeof(int) * (size_t)(NC * CBN), 256);
  int*   node_ptr   = (int*)p;   p = align_up(p + sizeof(int) * (size_t)NPTR, 256);
  float* dinv       = (float*)p; p = align_up(p + sizeof(float) * N_NODES, 256);
  char*  recs_mem   = p;         p = align_up(p + sizeof(uint2) * (size_t)N_EDGES, 256);
  uint2* recs2      = (uint2*)p; p = align_up(p + sizeof(uint2) * (size_t)REC2_CAP, 256);

  uint2* recs = (uint2*)recs_mem;
  unsigned short* outbA = (unsigned short*)recs_mem;  // alias (recs dead after sort)
  unsigned short* outbB = (unsigned short*)align_up(
      recs_mem + sizeof(unsigned short) * (size_t)N_NODES * D, 256);
  int* blk_hist = (int*)recs2;   // alias (dead before recs2 is written)

  // ---- one-time build: coarse sort (256-node bins) -> per-node runs ----
  k_bincount<<<NBB, BLKS, 0, stream>>>(col, blk_hist);
  k_colscan<<<NC, BLK, 0, stream>>>(blk_hist, bin_cnt);
  k_scan<<<1, 1024, 0, stream>>>(bin_cnt, coarse_ptr, NC, N_EDGES);
  k_binscatter<<<NBB, BLKS, 0, stream>>>(row, col, edge_attr, coarse_ptr, blk_hist, recs);
  k_cntnode<<<NC, BLKS, 0, stream>>>(recs, coarse_ptr, cnt_g, pad_cnt);
  k_scan<<<1, 1024, 0, stream>>>(pad_cnt, pad_ptr, NC, -1);
  k_sortscatter<<<NC, BLKS, 0, stream>>>(recs, coarse_ptr, cnt_g, pad_ptr, node_ptr, recs2);
  k_dinv2<<<NBN, BLK, 0, stream>>>(node_ptr, recs2, dinv);

  // ---- layers: lin #2 fused into agg #1; classifier separate (MODE 0) ----
  k_lin<<<NBN, BLK, 0, stream>>>(x, lin_w, dinv, outbA);
  k_agg<1><<<NP, BLK, 0, stream>>>(node_ptr, recs2, dinv, outbA,
                                   node_w, node_b, conv_b, ln_g, ln_b,
                                   lin_w + D * D, outbB);
  k_agg<0><<<NP, BLK, 0, stream>>>(node_ptr, recs2, dinv, outbB,
                                   node_w + D * D, node_b + D, conv_b + D,
                                   ln_g + D, ln_b + D,
                                   nullptr, outbA);
  k_cls<<<NBN, BLK, 0, stream>>>(outbA, w1, b1, w2, b2, out);
}